// Round 1
// baseline (438.980 us; speedup 1.0000x reference)
//
#include <hip/hip_runtime.h>

#define BSZN 8
#define TT 4096
#define DIN 512
#define PP 256
#define HHH 256
#define DOUT 512
#define NROWS (BSZN * TT)   // 32768
#define LCH 128             // scan chunk length
#define NC (TT / LCH)       // 32 chunks

// ---------------------------------------------------------------------------
// Tiled f32 GEMM: C[M,N] = A[M,K] * op(B) (+bias) (+relu)
//   BT=true : B is [N,K] row-major (k contiguous)  -> C[m,n] = sum_k A[m,k]*B[n,k]
//   BT=false: B is [K,N] row-major (n contiguous)  -> C[m,n] = sum_k A[m,k]*B[k,n]
// 128x128 tile, BK=16, 256 threads, 8x8 micro-tile (split 4+4 cols/rows).
// All dims assumed multiples of tile sizes (true for this problem).
// ---------------------------------------------------------------------------
template <int BM, int BN, int BK, bool BT, bool RELU, bool BIAS>
__global__ __launch_bounds__(256) void gemm_f32(
    const float* __restrict__ A, const float* __restrict__ Bm,
    const float* __restrict__ bias, float* __restrict__ C,
    int M, int N, int K) {
  __shared__ float As[BK][BM + 4];
  __shared__ float Bs[BK][BN + 4];

  const int tid = threadIdx.x;
  const int tx = tid & 15;   // 0..15 -> output cols
  const int ty = tid >> 4;   // 0..15 -> output rows
  const int m0 = blockIdx.x * BM;
  const int n0 = blockIdx.y * BN;

  float acc[8][8];
#pragma unroll
  for (int i = 0; i < 8; ++i)
#pragma unroll
    for (int j = 0; j < 8; ++j) acc[i][j] = 0.f;

  for (int k0 = 0; k0 < K; k0 += BK) {
    // ---- stage A tile, transposed to As[k][m] ----
#pragma unroll
    for (int t2 = 0; t2 < 2; ++t2) {
      int f = tid + t2 * 256;          // 0..511
      int row = f >> 2;                // 0..127
      int kc = (f & 3) << 2;           // 0,4,8,12
      const float4 av = *(const float4*)(A + (size_t)(m0 + row) * K + k0 + kc);
      As[kc + 0][row] = av.x;
      As[kc + 1][row] = av.y;
      As[kc + 2][row] = av.z;
      As[kc + 3][row] = av.w;
    }
    // ---- stage B tile to Bs[k][n] ----
    if constexpr (BT) {
#pragma unroll
      for (int t2 = 0; t2 < 2; ++t2) {
        int f = tid + t2 * 256;
        int n = f >> 2;
        int kc = (f & 3) << 2;
        const float4 bv = *(const float4*)(Bm + (size_t)(n0 + n) * K + k0 + kc);
        Bs[kc + 0][n] = bv.x;
        Bs[kc + 1][n] = bv.y;
        Bs[kc + 2][n] = bv.z;
        Bs[kc + 3][n] = bv.w;
      }
    } else {
#pragma unroll
      for (int t2 = 0; t2 < 2; ++t2) {
        int f = tid + t2 * 256;
        int kr = f >> 5;                // 0..15
        int nc = (f & 31) << 2;         // 0..124
        const float4 bv = *(const float4*)(Bm + (size_t)(k0 + kr) * N + n0 + nc);
        *(float4*)(&Bs[kr][nc]) = bv;
      }
    }
    __syncthreads();

#pragma unroll
    for (int k = 0; k < BK; ++k) {
      const float4 a0 = *(const float4*)(&As[k][ty * 4]);
      const float4 a1 = *(const float4*)(&As[k][64 + ty * 4]);
      const float4 b0 = *(const float4*)(&Bs[k][tx * 4]);
      const float4 b1 = *(const float4*)(&Bs[k][64 + tx * 4]);
      const float av[8] = {a0.x, a0.y, a0.z, a0.w, a1.x, a1.y, a1.z, a1.w};
      const float bv[8] = {b0.x, b0.y, b0.z, b0.w, b1.x, b1.y, b1.z, b1.w};
#pragma unroll
      for (int i = 0; i < 8; ++i)
#pragma unroll
        for (int j = 0; j < 8; ++j) acc[i][j] = fmaf(av[i], bv[j], acc[i][j]);
    }
    __syncthreads();
  }

  // ---- epilogue ----
#pragma unroll
  for (int i = 0; i < 8; ++i) {
    const int r = m0 + ((i < 4) ? (ty * 4 + i) : (64 + ty * 4 + (i - 4)));
#pragma unroll
    for (int jh = 0; jh < 2; ++jh) {
      const int cb = n0 + jh * 64 + tx * 4;
      float4 v;
      v.x = acc[i][jh * 4 + 0];
      v.y = acc[i][jh * 4 + 1];
      v.z = acc[i][jh * 4 + 2];
      v.w = acc[i][jh * 4 + 3];
      if constexpr (BIAS) {
        v.x += bias[cb + 0];
        v.y += bias[cb + 1];
        v.z += bias[cb + 2];
        v.w += bias[cb + 3];
      }
      if constexpr (RELU) {
        v.x = fmaxf(v.x, 0.f);
        v.y = fmaxf(v.y, 0.f);
        v.z = fmaxf(v.z, 0.f);
        v.w = fmaxf(v.w, 0.f);
      }
      *(float4*)(C + (size_t)r * N + cb) = v;
    }
  }
}

// ---------------------------------------------------------------------------
// Chunked parallel scan: h_t = a*h_{t-1} + u_t  (diagonal per channel h)
// pass 1: per-(b,chunk,h) local scan end value (zero init) -> carry
// pass 2: per-(b,h) sequential prefix over NC chunks: incoming state per chunk
// pass 3: re-run local scans seeded with true incoming state, write hs in
//         place over u.
// ---------------------------------------------------------------------------
__global__ __launch_bounds__(256) void scan_carry_k(
    const float* __restrict__ u, const float* __restrict__ a,
    float* __restrict__ carry) {
  const int bc = blockIdx.x;       // b*NC + c
  const int h = threadIdx.x;       // 0..255
  const float ah = a[h];
  const float* p = u + (size_t)bc * LCH * HHH + h;
  float e = 0.f;
#pragma unroll 4
  for (int i = 0; i < LCH; ++i) e = fmaf(ah, e, p[(size_t)i * HHH]);
  carry[(size_t)bc * HHH + h] = e;
}

__global__ __launch_bounds__(256) void carry_prefix_k(
    const float* __restrict__ carry, const float* __restrict__ a,
    float* __restrict__ prefix) {
  const int b = blockIdx.x;        // 0..BSZN-1
  const int h = threadIdx.x;       // 0..255
  const float ah = a[h];
  float aL = ah;                    // a^(2^7) = a^128 = a^LCH
#pragma unroll
  for (int j = 0; j < 7; ++j) aL *= aL;
  float e = 0.f;
  for (int k = 0; k < NC; ++k) {
    const size_t idx = ((size_t)b * NC + k) * HHH + h;
    prefix[idx] = e;                // state entering chunk k
    e = fmaf(aL, e, carry[idx]);
  }
}

__global__ __launch_bounds__(256) void scan_write_k(
    float* __restrict__ u, const float* __restrict__ a,
    const float* __restrict__ prefix) {
  const int bc = blockIdx.x;
  const int h = threadIdx.x;
  const float ah = a[h];
  float e = prefix[(size_t)bc * HHH + h];
  float* p = u + (size_t)bc * LCH * HHH + h;
#pragma unroll 4
  for (int i = 0; i < LCH; ++i) {
    const float v = p[(size_t)i * HHH];
    e = fmaf(ah, e, v);
    p[(size_t)i * HHH] = e;
  }
}

// ---------------------------------------------------------------------------
extern "C" void kernel_launch(void* const* d_in, const int* in_sizes, int n_in,
                              void* d_out, int out_size, void* d_ws,
                              size_t ws_size, hipStream_t stream) {
  const float* x  = (const float*)d_in[0];   // [8,4096,512]
  const float* a  = (const float*)d_in[1];   // [256]
  const float* Bm = (const float*)d_in[2];   // [P=256,H=256]
  const float* Cm = (const float*)d_in[3];   // [H=256,P=256]
  const float* Wi = (const float*)d_in[4];   // [P=256,DIN=512]
  const float* bi = (const float*)d_in[5];   // [256]
  const float* Wo = (const float*)d_in[6];   // [DOUT=512,P=256]
  const float* bo = (const float*)d_in[7];   // [512]
  float* out = (float*)d_out;                // [8,4096,512]

  float* ws = (float*)d_ws;
  float* x_proj = ws;                               // NROWS*PP      (32 MB)
  float* u      = x_proj + (size_t)NROWS * PP;      // NROWS*HHH     (32 MB), becomes hs in place
  float* CWT    = u + (size_t)NROWS * HHH;          // DOUT*HHH      (0.5 MB)
  float* carry  = CWT + (size_t)DOUT * HHH;         // BSZN*NC*HHH
  float* prefix = carry + (size_t)BSZN * NC * HHH;  // BSZN*NC*HHH

  // CWT[o,h] = sum_p Wo[o,p] * C[h,p]   (fuses y_seq@C and @Wo^T into one GEMM)
  gemm_f32<128, 128, 16, true, false, false>
      <<<dim3(DOUT / 128, HHH / 128), 256, 0, stream>>>(Wo, Cm, nullptr, CWT,
                                                        DOUT, HHH, PP);
  // x_proj = relu(x @ Wi^T + bi)
  gemm_f32<128, 128, 16, true, true, true>
      <<<dim3(NROWS / 128, PP / 128), 256, 0, stream>>>(x, Wi, bi, x_proj,
                                                        NROWS, PP, DIN);
  // u = x_proj @ B   (B is [P,H], n-contiguous)
  gemm_f32<128, 128, 16, false, false, false>
      <<<dim3(NROWS / 128, HHH / 128), 256, 0, stream>>>(x_proj, Bm, nullptr,
                                                         u, NROWS, HHH, PP);
  // diagonal scan over T (chunked, 3 passes); hs overwrites u in place
  scan_carry_k<<<BSZN * NC, 256, 0, stream>>>(u, a, carry);
  carry_prefix_k<<<BSZN, HHH, 0, stream>>>(carry, a, prefix);
  scan_write_k<<<BSZN * NC, 256, 0, stream>>>(u, a, prefix);
  // out = hs @ CWT^T + bo
  gemm_f32<128, 128, 16, true, false, true>
      <<<dim3(NROWS / 128, DOUT / 128), 256, 0, stream>>>(u, CWT, bo, out,
                                                          NROWS, DOUT, HHH);
}

// Round 2
// 217.459 us; speedup vs baseline: 2.0187x; 2.0187x over previous
//
#include <hip/hip_runtime.h>

#define BSZN 8
#define TT 4096
#define DIN 512
#define PP 256
#define HHH 256
#define DOUT 512
#define NROWS (BSZN * TT)   // 32768
#define LCH 128             // scan chunk length
#define NC (TT / LCH)       // 32 chunks

typedef __attribute__((ext_vector_type(8))) short bf16x8;
typedef __attribute__((ext_vector_type(4))) float f32x4;

#define GLOBAL_AS __attribute__((address_space(1)))
#define LDS_AS __attribute__((address_space(3)))

static __device__ __forceinline__ void gld_lds16(const void* g, void* l) {
  __builtin_amdgcn_global_load_lds((const GLOBAL_AS unsigned int*)g,
                                   (LDS_AS unsigned int*)l, 16, 0, 0);
}

static __device__ __forceinline__ unsigned short f2bf(float x) {
  union { float f; unsigned u; } t{x};
  unsigned r = t.u + 0x7fffu + ((t.u >> 16) & 1u);  // RNE
  return (unsigned short)(r >> 16);
}

// ---------------------------------------------------------------------------
// MFMA bf16 GEMM, m97 structure: C[M,N] = A[M,K] * B^T (+bias) (+relu)
//   A: f32 (converted during LDS staging) if A_F32, else bf16 via global_load_lds
//   B: bf16 [N,K] row-major (k-contiguous), via global_load_lds width=16
// 128x128 tile, BK=32, 256 threads (4 waves, each 64x64 = 4x4 MFMA tiles).
// ---------------------------------------------------------------------------
template <bool A_F32, bool RELU, bool BIAS, bool OUT_BF16>
__global__ __launch_bounds__(256) void gemm_mfma(
    const void* __restrict__ Ap, const unsigned short* __restrict__ Bp,
    const float* __restrict__ bias, void* __restrict__ Cp,
    int M, int N, int K) {
  __shared__ alignas(16) char smem[16384];
  char* As = smem;           // [128][32] bf16, row stride 64 B (NO padding: gld_lds)
  char* Bs = smem + 8192;    // [128][32] bf16

  const int tid = threadIdx.x;
  const int wave = tid >> 6;
  const int lane = tid & 63;
  const int m0 = blockIdx.x * 128;
  const int n0 = blockIdx.y * 128;
  const int wrow = (wave >> 1) * 64;
  const int wcol = (wave & 1) * 64;

  f32x4 acc[4][4];
#pragma unroll
  for (int i = 0; i < 4; ++i)
#pragma unroll
    for (int j = 0; j < 4; ++j) acc[i][j] = f32x4{0.f, 0.f, 0.f, 0.f};

  for (int k0 = 0; k0 < K; k0 += 32) {
    // ---- stage A tile ----
    if constexpr (A_F32) {
      const float* A = (const float*)Ap;
#pragma unroll
      for (int it = 0; it < 4; ++it) {
        const int f = it * 256 + tid;       // 0..1023
        const int r = f >> 3;               // 0..127
        const int c = (f & 7) * 4;          // 0,4,..,28
        const float4 v = *(const float4*)(A + (size_t)(m0 + r) * K + k0 + c);
        uint2 w;
        w.x = (unsigned)f2bf(v.x) | ((unsigned)f2bf(v.y) << 16);
        w.y = (unsigned)f2bf(v.z) | ((unsigned)f2bf(v.w) << 16);
        *(uint2*)(As + r * 64 + c * 2) = w;
      }
    } else {
      const unsigned short* A = (const unsigned short*)Ap;
#pragma unroll
      for (int it = 0; it < 2; ++it) {
        const int r = it * 64 + wave * 16 + (lane >> 2);   // 0..127
        const int cB = (lane & 3) * 16;                    // byte col 0..48
        gld_lds16((const char*)(A + (size_t)(m0 + r) * K + k0) + cB,
                  As + r * 64 + cB);
      }
    }
    // ---- stage B tile (always bf16, k-contiguous) ----
#pragma unroll
    for (int it = 0; it < 2; ++it) {
      const int r = it * 64 + wave * 16 + (lane >> 2);
      const int cB = (lane & 3) * 16;
      gld_lds16((const char*)(Bp + (size_t)(n0 + r) * K + k0) + cB,
                Bs + r * 64 + cB);
    }
    __syncthreads();

    bf16x8 af[4], bf[4];
#pragma unroll
    for (int mi = 0; mi < 4; ++mi)
      af[mi] = *(const bf16x8*)(As + (wrow + mi * 16 + (lane & 15)) * 64 +
                                (lane >> 4) * 16);
#pragma unroll
    for (int ni = 0; ni < 4; ++ni)
      bf[ni] = *(const bf16x8*)(Bs + (wcol + ni * 16 + (lane & 15)) * 64 +
                                (lane >> 4) * 16);
#pragma unroll
    for (int mi = 0; mi < 4; ++mi)
#pragma unroll
      for (int ni = 0; ni < 4; ++ni)
        acc[mi][ni] = __builtin_amdgcn_mfma_f32_16x16x32_bf16(
            af[mi], bf[ni], acc[mi][ni], 0, 0, 0);
    __syncthreads();
  }

  // ---- epilogue: C/D layout col=lane&15, row=(lane>>4)*4+reg ----
#pragma unroll
  for (int mi = 0; mi < 4; ++mi)
#pragma unroll
    for (int ni = 0; ni < 4; ++ni)
#pragma unroll
      for (int reg = 0; reg < 4; ++reg) {
        const int row = m0 + wrow + mi * 16 + (lane >> 4) * 4 + reg;
        const int col = n0 + wcol + ni * 16 + (lane & 15);
        float v = acc[mi][ni][reg];
        if constexpr (BIAS) v += bias[col];
        if constexpr (RELU) v = fmaxf(v, 0.f);
        if constexpr (OUT_BF16)
          ((unsigned short*)Cp)[(size_t)row * N + col] = f2bf(v);
        else
          ((float*)Cp)[(size_t)row * N + col] = v;
      }
}

// ---------------------------------------------------------------------------
// Weight conversion: Wi,Wo,C -> bf16 (same layout); B [P,H] -> B_bT [H,P] bf16
// ---------------------------------------------------------------------------
__global__ __launch_bounds__(256) void conv_w_k(
    const float* __restrict__ Wi, const float* __restrict__ Wo,
    const float* __restrict__ Cm, const float* __restrict__ Bm,
    unsigned short* __restrict__ Wi_b, unsigned short* __restrict__ Wo_b,
    unsigned short* __restrict__ C_b, unsigned short* __restrict__ B_bT) {
  const int b = blockIdx.x;
  const int tid = threadIdx.x;
  if (b < 320) {  // vector f32->bf16 converts
    const float* src;
    unsigned short* dst;
    int idx;
    if (b < 128) { src = Wi; dst = Wi_b; idx = b * 1024 + tid * 4; }
    else if (b < 256) { src = Wo; dst = Wo_b; idx = (b - 128) * 1024 + tid * 4; }
    else { src = Cm; dst = C_b; idx = (b - 256) * 1024 + tid * 4; }
    const float4 v = *(const float4*)(src + idx);
    uint2 w;
    w.x = (unsigned)f2bf(v.x) | ((unsigned)f2bf(v.y) << 16);
    w.y = (unsigned)f2bf(v.z) | ((unsigned)f2bf(v.w) << 16);
    *(uint2*)(dst + idx) = w;
  } else {  // B transpose: B_bT[h][p] = B[p][h]
    const int p = b - 320;      // 0..255
    const int h = tid;          // 0..255
    B_bT[(size_t)h * PP + p] = f2bf(Bm[(size_t)p * HHH + h]);
  }
}

// ---------------------------------------------------------------------------
// Chunked parallel scan: h_t = a*h_{t-1} + u_t (diagonal); f32 throughout.
// ---------------------------------------------------------------------------
__global__ __launch_bounds__(256) void scan_carry_k(
    const float* __restrict__ u, const float* __restrict__ a,
    float* __restrict__ carry) {
  const int bc = blockIdx.x;
  const int h = threadIdx.x;
  const float ah = a[h];
  const float* p = u + (size_t)bc * LCH * HHH + h;
  float e = 0.f;
#pragma unroll 4
  for (int i = 0; i < LCH; ++i) e = fmaf(ah, e, p[(size_t)i * HHH]);
  carry[(size_t)bc * HHH + h] = e;
}

__global__ __launch_bounds__(256) void carry_prefix_k(
    const float* __restrict__ carry, const float* __restrict__ a,
    float* __restrict__ prefix) {
  const int b = blockIdx.x;
  const int h = threadIdx.x;
  const float ah = a[h];
  float aL = ah;
#pragma unroll
  for (int j = 0; j < 7; ++j) aL *= aL;   // a^128 = a^LCH
  float e = 0.f;
  for (int k = 0; k < NC; ++k) {
    const size_t idx = ((size_t)b * NC + k) * HHH + h;
    prefix[idx] = e;
    e = fmaf(aL, e, carry[idx]);
  }
}

// pass 3: local scans seeded with true incoming state; write hs as bf16
__global__ __launch_bounds__(256) void scan_write_k(
    const float* __restrict__ u, const float* __restrict__ a,
    const float* __restrict__ prefix, unsigned short* __restrict__ hs_b) {
  const int bc = blockIdx.x;
  const int h = threadIdx.x;
  const float ah = a[h];
  float e = prefix[(size_t)bc * HHH + h];
  const float* p = u + (size_t)bc * LCH * HHH + h;
  unsigned short* q = hs_b + (size_t)bc * LCH * HHH + h;
#pragma unroll 4
  for (int i = 0; i < LCH; ++i) {
    e = fmaf(ah, e, p[(size_t)i * HHH]);
    q[(size_t)i * HHH] = f2bf(e);
  }
}

// ---------------------------------------------------------------------------
extern "C" void kernel_launch(void* const* d_in, const int* in_sizes, int n_in,
                              void* d_out, int out_size, void* d_ws,
                              size_t ws_size, hipStream_t stream) {
  const float* x  = (const float*)d_in[0];   // [8,4096,512]
  const float* a  = (const float*)d_in[1];   // [256]
  const float* Bm = (const float*)d_in[2];   // [P,H]
  const float* Cm = (const float*)d_in[3];   // [H,P]
  const float* Wi = (const float*)d_in[4];   // [P,DIN]
  const float* bi = (const float*)d_in[5];   // [P]
  const float* Wo = (const float*)d_in[6];   // [DOUT,P]
  const float* bo = (const float*)d_in[7];   // [DOUT]
  float* out = (float*)d_out;                // [8,4096,512] f32

  char* ws = (char*)d_ws;
  float* u = (float*)ws;                                   // 33.55 MB f32
  ws += (size_t)NROWS * HHH * 4;
  unsigned short* xproj_b = (unsigned short*)ws;           // 16.78 MB bf16
  ws += (size_t)NROWS * PP * 2;
  unsigned short* hs_b = (unsigned short*)ws;              // 16.78 MB bf16
  ws += (size_t)NROWS * HHH * 2;
  unsigned short* Wi_b = (unsigned short*)ws; ws += (size_t)PP * DIN * 2;
  unsigned short* Wo_b = (unsigned short*)ws; ws += (size_t)DOUT * PP * 2;
  unsigned short* C_b  = (unsigned short*)ws; ws += (size_t)HHH * PP * 2;
  unsigned short* B_bT = (unsigned short*)ws; ws += (size_t)HHH * PP * 2;
  unsigned short* CWT_b = (unsigned short*)ws; ws += (size_t)DOUT * HHH * 2;
  float* carry  = (float*)ws; ws += (size_t)BSZN * NC * HHH * 4;
  float* prefix = (float*)ws;

  // 0. convert weights (Wi,Wo,C -> bf16; B -> transposed bf16)
  conv_w_k<<<576, 256, 0, stream>>>(Wi, Wo, Cm, Bm, Wi_b, Wo_b, C_b, B_bT);
  // 1. CWT[o,h] = sum_p Wo[o,p]*C[h,p]  (bf16 out)
  gemm_mfma<false, false, false, true>
      <<<dim3(DOUT / 128, HHH / 128), 256, 0, stream>>>(Wo_b, C_b, nullptr,
                                                        CWT_b, DOUT, HHH, PP);
  // 2. x_proj = relu(x @ Wi^T + bi)  (f32 A converted in staging; bf16 out)
  gemm_mfma<true, true, true, true>
      <<<dim3(NROWS / 128, PP / 128), 256, 0, stream>>>(x, Wi_b, bi, xproj_b,
                                                        NROWS, PP, DIN);
  // 3. u = x_proj @ B  (= xproj_b @ B_bT^T; f32 out for the scan)
  gemm_mfma<false, false, false, false>
      <<<dim3(NROWS / 128, HHH / 128), 256, 0, stream>>>(xproj_b, B_bT,
                                                         nullptr, u, NROWS,
                                                         HHH, PP);
  // 4. diagonal scan over T (chunked, 3 passes); hs written as bf16
  scan_carry_k<<<BSZN * NC, 256, 0, stream>>>(u, a, carry);
  carry_prefix_k<<<BSZN, HHH, 0, stream>>>(carry, a, prefix);
  scan_write_k<<<BSZN * NC, 256, 0, stream>>>(u, a, prefix, hs_b);
  // 5. out = hs @ CWT^T + bo  (f32 out)
  gemm_mfma<false, false, true, false>
      <<<dim3(NROWS / 128, DOUT / 128), 256, 0, stream>>>(hs_b, CWT_b, bo, out,
                                                          NROWS, DOUT, HHH);
}

// Round 3
// 196.304 us; speedup vs baseline: 2.2362x; 1.1078x over previous
//
#include <hip/hip_runtime.h>

#define BSZN 8
#define TT 4096
#define DIN 512
#define PP 256
#define HHH 256
#define DOUT 512
#define NROWS (BSZN * TT)   // 32768
#define LCH 128             // scan chunk length == GEMM row tile
#define NC (TT / LCH)       // 32 chunks per batch

typedef __attribute__((ext_vector_type(8))) short bf16x8;
typedef __attribute__((ext_vector_type(4))) float f32x4;

#define GLOBAL_AS __attribute__((address_space(1)))
#define LDS_AS __attribute__((address_space(3)))

static __device__ __forceinline__ void gld_lds16(const void* g, void* l) {
  __builtin_amdgcn_global_load_lds((const GLOBAL_AS unsigned int*)g,
                                   (LDS_AS unsigned int*)l, 16, 0, 0);
}

static __device__ __forceinline__ unsigned short f2bf(float x) {
  union { float f; unsigned u; } t{x};
  unsigned r = t.u + 0x7fffu + ((t.u >> 16) & 1u);  // RNE
  return (unsigned short)(r >> 16);
}

// ---------------------------------------------------------------------------
// Small MFMA bf16 GEMM (R2-verified), used only for CWT = Wo @ C^T (bf16 out).
// ---------------------------------------------------------------------------
__global__ __launch_bounds__(256) void gemm_cwt(
    const unsigned short* __restrict__ Ap, const unsigned short* __restrict__ Bp,
    unsigned short* __restrict__ Cp, int M, int N, int K) {
  __shared__ alignas(16) char smem[16384];
  char* As = smem;
  char* Bs = smem + 8192;
  const int tid = threadIdx.x, wave = tid >> 6, lane = tid & 63;
  const int m0 = blockIdx.x * 128, n0 = blockIdx.y * 128;
  const int wrow = (wave >> 1) * 64, wcol = (wave & 1) * 64;

  f32x4 acc[4][4];
#pragma unroll
  for (int i = 0; i < 4; ++i)
#pragma unroll
    for (int j = 0; j < 4; ++j) acc[i][j] = f32x4{0.f, 0.f, 0.f, 0.f};

  for (int k0 = 0; k0 < K; k0 += 32) {
#pragma unroll
    for (int it = 0; it < 2; ++it) {
      const int r = it * 64 + wave * 16 + (lane >> 2);
      const int cB = (lane & 3) * 16;
      gld_lds16((const char*)(Ap + (size_t)(m0 + r) * K + k0) + cB, As + r * 64 + cB);
      gld_lds16((const char*)(Bp + (size_t)(n0 + r) * K + k0) + cB, Bs + r * 64 + cB);
    }
    __syncthreads();
    bf16x8 af[4], bfv[4];
#pragma unroll
    for (int mi = 0; mi < 4; ++mi)
      af[mi] = *(const bf16x8*)(As + (wrow + mi * 16 + (lane & 15)) * 64 + (lane >> 4) * 16);
#pragma unroll
    for (int ni = 0; ni < 4; ++ni)
      bfv[ni] = *(const bf16x8*)(Bs + (wcol + ni * 16 + (lane & 15)) * 64 + (lane >> 4) * 16);
#pragma unroll
    for (int mi = 0; mi < 4; ++mi)
#pragma unroll
      for (int ni = 0; ni < 4; ++ni)
        acc[mi][ni] = __builtin_amdgcn_mfma_f32_16x16x32_bf16(af[mi], bfv[ni], acc[mi][ni], 0, 0, 0);
    __syncthreads();
  }
#pragma unroll
  for (int mi = 0; mi < 4; ++mi)
#pragma unroll
    for (int ni = 0; ni < 4; ++ni)
#pragma unroll
      for (int reg = 0; reg < 4; ++reg) {
        const int row = m0 + wrow + mi * 16 + (lane >> 4) * 4 + reg;
        const int col = n0 + wcol + ni * 16 + (lane & 15);
        Cp[(size_t)row * N + col] = f2bf(acc[mi][ni][reg]);
      }
}

// ---------------------------------------------------------------------------
// Weight prep: Wi,Wo,C -> bf16; B -> B^T bf16; zero lookback flags.
// ---------------------------------------------------------------------------
__global__ __launch_bounds__(256) void conv_w_k(
    const float* __restrict__ Wi, const float* __restrict__ Wo,
    const float* __restrict__ Cm, const float* __restrict__ Bm,
    unsigned short* __restrict__ Wi_b, unsigned short* __restrict__ Wo_b,
    unsigned short* __restrict__ C_b, unsigned short* __restrict__ B_bT,
    int* __restrict__ flag_g) {
  const int b = blockIdx.x;
  const int tid = threadIdx.x;
  if (b < 320) {
    const float* src;
    unsigned short* dst;
    int idx;
    if (b < 128) { src = Wi; dst = Wi_b; idx = b * 1024 + tid * 4; }
    else if (b < 256) { src = Wo; dst = Wo_b; idx = (b - 128) * 1024 + tid * 4; }
    else { src = Cm; dst = C_b; idx = (b - 256) * 1024 + tid * 4; }
    const float4 v = *(const float4*)(src + idx);
    uint2 w;
    w.x = (unsigned)f2bf(v.x) | ((unsigned)f2bf(v.y) << 16);
    w.y = (unsigned)f2bf(v.z) | ((unsigned)f2bf(v.w) << 16);
    *(uint2*)(dst + idx) = w;
  } else if (b < 576) {
    const int p = b - 320;
    const int h = tid;
    B_bT[(size_t)h * PP + p] = f2bf(Bm[(size_t)p * HHH + h]);
  } else {
    // zero lookback flags (ws is poisoned 0xAA before every call!)
    flag_g[tid] = 0;
  }
}

// ---------------------------------------------------------------------------
// Mega-kernel: one block per (batch, chunk). 256 blocks == 256 CUs, all
// co-resident (64 KB LDS, grid 256) -> decoupled all-lookback is safe.
// Phases: in-proj GEMM (x f32->bf16 staged) -> u GEMM (xproj in LDS) ->
// LDS column scan + cross-chunk lookback fixup -> out GEMM -> store.
// Intermediates never touch HBM except 256 KB of carries.
// ---------------------------------------------------------------------------
__global__ __launch_bounds__(256, 1) void s4_mega(
    const float* __restrict__ x, const float* __restrict__ a,
    const unsigned short* __restrict__ Wi_b, const float* __restrict__ bi,
    const unsigned short* __restrict__ B_bT,
    const unsigned short* __restrict__ CWT_b, const float* __restrict__ bo,
    float* __restrict__ out, float* __restrict__ carry_g,
    int* __restrict__ flag_g) {
  __shared__ alignas(16) char smem[65536];
  char* As = smem;           // 8 KB  (phase 1 A staging)
  char* Bs = smem + 8192;    // 16 KB (phase 1 Wi staging)

  const int tid = threadIdx.x, wave = tid >> 6, lane = tid & 63;
  const int bc = blockIdx.x, b = bc >> 5, c = bc & 31;
  const size_t row0 = (size_t)bc * LCH;
  const int wrow = (wave >> 1) * 64;   // wave row base (0/64)
  const int wcol = (wave & 1) * 128;   // wave col base (0/128)
  const int l15 = lane & 15, q = lane >> 4;

  // ============ phase 1: acc = relu-pending x @ Wi^T ============
  f32x4 acc[4][8];
#pragma unroll
  for (int i = 0; i < 4; ++i)
#pragma unroll
    for (int j = 0; j < 8; ++j) acc[i][j] = f32x4{0.f, 0.f, 0.f, 0.f};

  for (int k0 = 0; k0 < DIN; k0 += 32) {
#pragma unroll
    for (int it = 0; it < 4; ++it) {           // x f32 -> bf16 into As[128][32]
      const int f = it * 256 + tid;
      const int r = f >> 3, ck = (f & 7) * 4;
      const float4 v = *(const float4*)(x + (row0 + r) * DIN + k0 + ck);
      uint2 w;
      w.x = (unsigned)f2bf(v.x) | ((unsigned)f2bf(v.y) << 16);
      w.y = (unsigned)f2bf(v.z) | ((unsigned)f2bf(v.w) << 16);
      *(uint2*)(As + r * 64 + ck * 2) = w;
    }
#pragma unroll
    for (int it = 0; it < 4; ++it) {           // Wi tile [256][32] via gld_lds
      const int R0 = it * 64 + wave * 16;
      const int row = R0 + (lane >> 2), cB = (lane & 3) * 16;
      gld_lds16((const char*)(Wi_b + (size_t)row * DIN + k0) + cB, Bs + row * 64 + cB);
    }
    __syncthreads();
    bf16x8 af[4], bfv[8];
#pragma unroll
    for (int mi = 0; mi < 4; ++mi)
      af[mi] = *(const bf16x8*)(As + (wrow + mi * 16 + l15) * 64 + q * 16);
#pragma unroll
    for (int ni = 0; ni < 8; ++ni)
      bfv[ni] = *(const bf16x8*)(Bs + (wcol + ni * 16 + l15) * 64 + q * 16);
#pragma unroll
    for (int mi = 0; mi < 4; ++mi)
#pragma unroll
      for (int ni = 0; ni < 8; ++ni)
        acc[mi][ni] = __builtin_amdgcn_mfma_f32_16x16x32_bf16(af[mi], bfv[ni], acc[mi][ni], 0, 0, 0);
    __syncthreads();
  }

  // ============ phase 1.5: relu+bias -> xp LDS bf16 [128][256] ============
  unsigned short* xp = (unsigned short*)smem;
#pragma unroll
  for (int mi = 0; mi < 4; ++mi)
#pragma unroll
    for (int ni = 0; ni < 8; ++ni) {
      const int col = wcol + ni * 16 + l15;
      const float bb = bi[col];
#pragma unroll
      for (int reg = 0; reg < 4; ++reg) {
        const int row = wrow + mi * 16 + q * 4 + reg;
        float v = acc[mi][ni][reg] + bb;
        v = fmaxf(v, 0.f);
        xp[row * 256 + col] = f2bf(v);
      }
    }
  __syncthreads();

  // ============ phase 2: u = xp @ B (B-frags direct from L2) ============
  f32x4 uacc[4][8];
#pragma unroll
  for (int i = 0; i < 4; ++i)
#pragma unroll
    for (int j = 0; j < 8; ++j) uacc[i][j] = f32x4{0.f, 0.f, 0.f, 0.f};
  for (int k0 = 0; k0 < PP; k0 += 32) {
    bf16x8 af[4], bfv[8];
#pragma unroll
    for (int mi = 0; mi < 4; ++mi)
      af[mi] = *(const bf16x8*)(xp + (wrow + mi * 16 + l15) * 256 + k0 + q * 8);
#pragma unroll
    for (int ni = 0; ni < 8; ++ni) {
      const int h = wcol + ni * 16 + l15;
      bfv[ni] = *(const bf16x8*)(B_bT + (size_t)h * PP + k0 + q * 8);
    }
#pragma unroll
    for (int mi = 0; mi < 4; ++mi)
#pragma unroll
      for (int ni = 0; ni < 8; ++ni)
        uacc[mi][ni] = __builtin_amdgcn_mfma_f32_16x16x32_bf16(af[mi], bfv[ni], uacc[mi][ni], 0, 0, 0);
  }
  __syncthreads();   // xp dead after this

  // ============ phase 3: local scan per column half in LDS ============
  float carry0 = 0.f, carry1 = 0.f;
  float* uL = (float*)smem;   // [128 rows][128 cols] f32 = 64 KB
#pragma unroll
  for (int kh = 0; kh < 2; ++kh) {
    if ((wave & 1) == kh) {
#pragma unroll
      for (int mi = 0; mi < 4; ++mi)
#pragma unroll
        for (int ni = 0; ni < 8; ++ni) {
          const int colh = ni * 16 + l15;
#pragma unroll
          for (int reg = 0; reg < 4; ++reg) {
            const int row = wrow + mi * 16 + q * 4 + reg;
            uL[row * 128 + colh] = uacc[mi][ni][reg];
          }
        }
    }
    __syncthreads();
    if (tid < 128) {   // thread t scans column t of this half
      const float ah = a[kh * 128 + tid];
      float l = 0.f;
#pragma unroll 4
      for (int i = 0; i < LCH; ++i) {
        l = fmaf(ah, l, uL[i * 128 + tid]);
        uL[i * 128 + tid] = l;
      }
      if (kh == 0) carry0 = l; else carry1 = l;
    }
    __syncthreads();
    if ((wave & 1) == kh) {
#pragma unroll
      for (int mi = 0; mi < 4; ++mi)
#pragma unroll
        for (int ni = 0; ni < 8; ++ni) {
          const int colh = ni * 16 + l15;
#pragma unroll
          for (int reg = 0; reg < 4; ++reg) {
            const int row = wrow + mi * 16 + q * 4 + reg;
            uacc[mi][ni][reg] = uL[row * 128 + colh];
          }
        }
    }
    __syncthreads();
  }

  // ============ phase 3.5: decoupled all-lookback across chunks ============
  if (tid < 128) {
    __hip_atomic_store(&carry_g[(size_t)bc * HHH + tid], carry0,
                       __ATOMIC_RELAXED, __HIP_MEMORY_SCOPE_AGENT);
    __hip_atomic_store(&carry_g[(size_t)bc * HHH + 128 + tid], carry1,
                       __ATOMIC_RELAXED, __HIP_MEMORY_SCOPE_AGENT);
  }
  __syncthreads();
  if (tid == 0) {
    __threadfence();
    __hip_atomic_store(&flag_g[bc], 1, __ATOMIC_RELEASE, __HIP_MEMORY_SCOPE_AGENT);
  }
  if (tid < c) {
    while (__hip_atomic_load(&flag_g[b * NC + tid], __ATOMIC_ACQUIRE,
                             __HIP_MEMORY_SCOPE_AGENT) == 0)
      __builtin_amdgcn_s_sleep(8);
  }
  __syncthreads();
  // incoming state P per column (Horner over predecessor carries)
  float P = 0.f;
  {
    const float ah = a[tid];
    float aL = ah;
#pragma unroll
    for (int j = 0; j < 7; ++j) aL *= aL;   // a^128 = a^LCH
    for (int j = 0; j < c; ++j)
      P = fmaf(aL, P,
               __hip_atomic_load(&carry_g[((size_t)b * NC + j) * HHH + tid],
                                 __ATOMIC_RELAXED, __HIP_MEMORY_SCOPE_AGENT));
  }
  float* PL = (float*)smem;  // uL fully consumed
  PL[tid] = P;
  __syncthreads();
  // fixup: hs_row = l_row + a^(row+1) * P
#pragma unroll
  for (int ni = 0; ni < 8; ++ni) {
    const int col = wcol + ni * 16 + l15;
    const float Pc = PL[col];
    const float A = a[col];
    const float A2 = A * A, A4 = A2 * A2, A8 = A4 * A4, A16 = A8 * A8;
    const float A32 = A16 * A16, A64 = A32 * A32;
    float base = A * ((q & 1) ? A4 : 1.f) * ((q & 2) ? A8 : 1.f) *
                 (wrow ? A64 : 1.f);       // a^(wrow+4q+1)
    float rowf = base;
#pragma unroll
    for (int mi = 0; mi < 4; ++mi) {
      float fr = rowf;
#pragma unroll
      for (int reg = 0; reg < 4; ++reg) {
        uacc[mi][ni][reg] = fmaf(fr, Pc, uacc[mi][ni][reg]);
        fr *= A;
      }
      rowf *= A16;                          // * a^16 per mi
    }
  }
  __syncthreads();   // PL consumed

  // ============ phase 4: out = hs @ CWT^T + bo ============
  unsigned short* hsL = (unsigned short*)smem;  // [128][256] bf16 = 64 KB
#pragma unroll
  for (int mi = 0; mi < 4; ++mi)
#pragma unroll
    for (int ni = 0; ni < 8; ++ni) {
      const int col = wcol + ni * 16 + l15;
#pragma unroll
      for (int reg = 0; reg < 4; ++reg) {
        const int row = wrow + mi * 16 + q * 4 + reg;
        hsL[row * 256 + col] = f2bf(uacc[mi][ni][reg]);
      }
    }
  __syncthreads();

  for (int n = 0; n < 4; ++n) {
    f32x4 oacc[4][4];
#pragma unroll
    for (int i = 0; i < 4; ++i)
#pragma unroll
      for (int j = 0; j < 4; ++j) oacc[i][j] = f32x4{0.f, 0.f, 0.f, 0.f};
    const int ocol0 = n * 128 + (wave & 1) * 64;
    for (int k0 = 0; k0 < HHH; k0 += 32) {
      bf16x8 af[4], bfv[4];
#pragma unroll
      for (int mi = 0; mi < 4; ++mi)
        af[mi] = *(const bf16x8*)(hsL + (wrow + mi * 16 + l15) * 256 + k0 + q * 8);
#pragma unroll
      for (int ni = 0; ni < 4; ++ni) {
        const int o = ocol0 + ni * 16 + l15;
        bfv[ni] = *(const bf16x8*)(CWT_b + (size_t)o * HHH + k0 + q * 8);
      }
#pragma unroll
      for (int mi = 0; mi < 4; ++mi)
#pragma unroll
        for (int ni = 0; ni < 4; ++ni)
          oacc[mi][ni] = __builtin_amdgcn_mfma_f32_16x16x32_bf16(af[mi], bfv[ni], oacc[mi][ni], 0, 0, 0);
    }
#pragma unroll
    for (int ni = 0; ni < 4; ++ni) {
      const int o = ocol0 + ni * 16 + l15;
      const float bb = bo[o];
#pragma unroll
      for (int mi = 0; mi < 4; ++mi)
#pragma unroll
        for (int reg = 0; reg < 4; ++reg) {
          const int row = wrow + mi * 16 + q * 4 + reg;
          out[(row0 + row) * DOUT + o] = oacc[mi][ni][reg] + bb;
        }
    }
  }
}

// ---------------------------------------------------------------------------
extern "C" void kernel_launch(void* const* d_in, const int* in_sizes, int n_in,
                              void* d_out, int out_size, void* d_ws,
                              size_t ws_size, hipStream_t stream) {
  const float* x  = (const float*)d_in[0];
  const float* a  = (const float*)d_in[1];
  const float* Bm = (const float*)d_in[2];
  const float* Cm = (const float*)d_in[3];
  const float* Wi = (const float*)d_in[4];
  const float* bi = (const float*)d_in[5];
  const float* Wo = (const float*)d_in[6];
  const float* bo = (const float*)d_in[7];
  float* out = (float*)d_out;

  char* ws = (char*)d_ws;
  unsigned short* Wi_b  = (unsigned short*)ws; ws += (size_t)PP * DIN * 2;
  unsigned short* Wo_b  = (unsigned short*)ws; ws += (size_t)DOUT * PP * 2;
  unsigned short* C_b   = (unsigned short*)ws; ws += (size_t)HHH * PP * 2;
  unsigned short* B_bT  = (unsigned short*)ws; ws += (size_t)HHH * PP * 2;
  unsigned short* CWT_b = (unsigned short*)ws; ws += (size_t)DOUT * HHH * 2;
  float* carry_g = (float*)ws; ws += (size_t)BSZN * NC * HHH * 4;
  int* flag_g = (int*)ws;

  // 1. weights -> bf16, B -> B^T, zero flags
  conv_w_k<<<577, 256, 0, stream>>>(Wi, Wo, Cm, Bm, Wi_b, Wo_b, C_b, B_bT, flag_g);
  // 2. CWT[o,h] = sum_p Wo[o,p] * C[h,p]
  gemm_cwt<<<dim3(DOUT / 128, HHH / 128), 256, 0, stream>>>(Wo_b, C_b, CWT_b,
                                                            DOUT, HHH, PP);
  // 3. everything else in one persistent kernel (256 blocks == 256 CUs)
  s4_mega<<<BSZN * NC, 256, 0, stream>>>(x, a, Wi_b, bi, B_bT, CWT_b, bo, out,
                                         carry_g, flag_g);
}

// Round 4
// 194.310 us; speedup vs baseline: 2.2592x; 1.0103x over previous
//
#include <hip/hip_runtime.h>

#define BSZN 8
#define TT 4096
#define DIN 512
#define PP 256
#define HHH 256
#define DOUT 512
#define LCH 64              // scan chunk length == row tile
#define NCH (TT / LCH)      // 64 chunks per batch
#define NBLK (BSZN * NCH)   // 512 blocks
#define XPS 264             // padded LDS row stride (bf16 elems) for xp/hsL

typedef __attribute__((ext_vector_type(8))) short bf16x8;
typedef __attribute__((ext_vector_type(4))) float f32x4;

#define GLOBAL_AS __attribute__((address_space(1)))
#define LDS_AS __attribute__((address_space(3)))

static __device__ __forceinline__ void gld_lds16(const void* g, void* l) {
  __builtin_amdgcn_global_load_lds((const GLOBAL_AS unsigned int*)g,
                                   (LDS_AS unsigned int*)l, 16, 0, 0);
}

static __device__ __forceinline__ unsigned short f2bf(float x) {
  union { float f; unsigned u; } t{x};
  unsigned r = t.u + 0x7fffu + ((t.u >> 16) & 1u);  // RNE
  return (unsigned short)(r >> 16);
}

static __device__ __forceinline__ float ld_carry(const float* p) {
  return __hip_atomic_load(p, __ATOMIC_RELAXED, __HIP_MEMORY_SCOPE_AGENT);
}

// ---------------------------------------------------------------------------
// Prep (one dispatch): Wi->bf16, B->B^T bf16, zero flags, CWT = Wo @ C^T
// (CWT blocks read f32 Wo/C and convert during staging).
// ---------------------------------------------------------------------------
__global__ __launch_bounds__(256) void prep_k(
    const float* __restrict__ Wi, const float* __restrict__ Wo,
    const float* __restrict__ Cm, const float* __restrict__ Bm,
    unsigned short* __restrict__ Wi_b, unsigned short* __restrict__ B_bT,
    unsigned short* __restrict__ CWT_b, int* __restrict__ flag_g) {
  __shared__ alignas(16) char smem[16384];
  const int b = blockIdx.x, tid = threadIdx.x;
  if (b < 128) {                       // Wi convert (256x512)
    const int idx = b * 1024 + tid * 4;
    const float4 v = *(const float4*)(Wi + idx);
    uint2 w;
    w.x = (unsigned)f2bf(v.x) | ((unsigned)f2bf(v.y) << 16);
    w.y = (unsigned)f2bf(v.z) | ((unsigned)f2bf(v.w) << 16);
    *(uint2*)(Wi_b + idx) = w;
  } else if (b < 384) {                // B transpose (PxH -> HxP)
    const int p = b - 128;
    B_bT[(size_t)tid * PP + p] = f2bf(Bm[(size_t)p * HHH + tid]);
  } else if (b == 384) {               // zero lookback flags (ws poisoned!)
    flag_g[tid] = 0;
    flag_g[tid + 256] = 0;
  } else {                             // CWT tiles: 8 blocks of 128x128
    const int t = b - 385;
    const int m0 = (t >> 1) * 128, n0 = (t & 1) * 128;
    char* As = smem;
    char* Bs = smem + 8192;
    const int wave = tid >> 6, lane = tid & 63;
    const int l15 = lane & 15, q = lane >> 4;
    const int wrow = (wave >> 1) * 64, wcol = (wave & 1) * 64;
    f32x4 acc[4][4];
#pragma unroll
    for (int i = 0; i < 4; ++i)
#pragma unroll
      for (int j = 0; j < 4; ++j) acc[i][j] = f32x4{0.f, 0.f, 0.f, 0.f};
    for (int k0 = 0; k0 < PP; k0 += 32) {
#pragma unroll
      for (int it = 0; it < 4; ++it) {   // stage Wo rows m0..m0+127 (f32->bf16)
        const int f = it * 256 + tid;
        const int r = f >> 3, ck = (f & 7) * 4;
        const float4 v = *(const float4*)(Wo + (size_t)(m0 + r) * PP + k0 + ck);
        uint2 w;
        w.x = (unsigned)f2bf(v.x) | ((unsigned)f2bf(v.y) << 16);
        w.y = (unsigned)f2bf(v.z) | ((unsigned)f2bf(v.w) << 16);
        *(uint2*)(As + r * 64 + ck * 2) = w;
      }
#pragma unroll
      for (int it = 0; it < 4; ++it) {   // stage C rows n0..n0+127
        const int f = it * 256 + tid;
        const int r = f >> 3, ck = (f & 7) * 4;
        const float4 v = *(const float4*)(Cm + (size_t)(n0 + r) * PP + k0 + ck);
        uint2 w;
        w.x = (unsigned)f2bf(v.x) | ((unsigned)f2bf(v.y) << 16);
        w.y = (unsigned)f2bf(v.z) | ((unsigned)f2bf(v.w) << 16);
        *(uint2*)(Bs + r * 64 + ck * 2) = w;
      }
      __syncthreads();
      bf16x8 af[4], bfv[4];
#pragma unroll
      for (int mi = 0; mi < 4; ++mi)
        af[mi] = *(const bf16x8*)(As + (wrow + mi * 16 + l15) * 64 + q * 16);
#pragma unroll
      for (int ni = 0; ni < 4; ++ni)
        bfv[ni] = *(const bf16x8*)(Bs + (wcol + ni * 16 + l15) * 64 + q * 16);
#pragma unroll
      for (int mi = 0; mi < 4; ++mi)
#pragma unroll
        for (int ni = 0; ni < 4; ++ni)
          acc[mi][ni] = __builtin_amdgcn_mfma_f32_16x16x32_bf16(
              af[mi], bfv[ni], acc[mi][ni], 0, 0, 0);
      __syncthreads();
    }
#pragma unroll
    for (int mi = 0; mi < 4; ++mi)
#pragma unroll
      for (int ni = 0; ni < 4; ++ni)
#pragma unroll
        for (int reg = 0; reg < 4; ++reg) {
          const int row = m0 + wrow + mi * 16 + q * 4 + reg;
          const int col = n0 + wcol + ni * 16 + l15;
          CWT_b[(size_t)row * HHH + col] = f2bf(acc[mi][ni][reg]);
        }
  }
}

// ---------------------------------------------------------------------------
// Mega: one block per (batch, 64-row chunk). 512 blocks, 2/CU co-resident.
// Wave w owns cols [w*64, w*64+64) -> each lane holds a full column's 64 rows
// => scan is register-local + shuffles. xp/hsL use padded stride XPS=264.
// ---------------------------------------------------------------------------
__global__ __launch_bounds__(256, 2) void s4_mega(
    const float* __restrict__ x, const float* __restrict__ a,
    const unsigned short* __restrict__ Wi_b, const float* __restrict__ bi,
    const unsigned short* __restrict__ B_bT,
    const unsigned short* __restrict__ CWT_b, const float* __restrict__ bo,
    float* __restrict__ out, float* __restrict__ carry_g,
    int* __restrict__ flag_g) {
  __shared__ alignas(16) char smem[64 * XPS * 2 + 1024];  // 33792 + PL 1 KB
  char* As = smem;            // phase1: x tile  [64][32] bf16 (4 KB)
  char* Bs = smem + 4096;     // phase1: Wi tile [256][32] bf16 (16 KB)
  float* PL = (float*)(smem + 64 * XPS * 2);  // 256 f32

  const int tid = threadIdx.x, wave = tid >> 6, lane = tid & 63;
  const int l15 = lane & 15, q = lane >> 4;
  const int bc = blockIdx.x, b = bc >> 6, c = bc & 63;
  const size_t row0 = (size_t)bc * LCH;
  const int wc = wave * 64;   // wave column base (phases 1-3)

  // ================= phase 1: xW = x @ Wi^T (64x256) =================
  f32x4 acc[4][4];
#pragma unroll
  for (int i = 0; i < 4; ++i)
#pragma unroll
    for (int j = 0; j < 4; ++j) acc[i][j] = f32x4{0.f, 0.f, 0.f, 0.f};

  float4 xv0, xv1;
  {
    const int f0 = tid, f1 = tid + 256;
    xv0 = *(const float4*)(x + (row0 + (f0 >> 3)) * DIN + (f0 & 7) * 4);
    xv1 = *(const float4*)(x + (row0 + (f1 >> 3)) * DIN + (f1 & 7) * 4);
  }
  for (int k0 = 0; k0 < DIN; k0 += 32) {
    {  // store prefetched x (f32->bf16) into As
      const int f0 = tid, f1 = tid + 256;
      uint2 w;
      w.x = (unsigned)f2bf(xv0.x) | ((unsigned)f2bf(xv0.y) << 16);
      w.y = (unsigned)f2bf(xv0.z) | ((unsigned)f2bf(xv0.w) << 16);
      *(uint2*)(As + (f0 >> 3) * 64 + (f0 & 7) * 8) = w;
      w.x = (unsigned)f2bf(xv1.x) | ((unsigned)f2bf(xv1.y) << 16);
      w.y = (unsigned)f2bf(xv1.z) | ((unsigned)f2bf(xv1.w) << 16);
      *(uint2*)(As + (f1 >> 3) * 64 + (f1 & 7) * 8) = w;
    }
#pragma unroll
    for (int it = 0; it < 4; ++it) {  // Wi tile via global_load_lds x4
      const int row = it * 64 + wave * 16 + (lane >> 2);
      const int cB = (lane & 3) * 16;
      gld_lds16((const char*)(Wi_b + (size_t)row * DIN + k0) + cB,
                Bs + row * 64 + cB);
    }
    __syncthreads();
    if (k0 + 32 < DIN) {  // prefetch next x tile into regs
      const int f0 = tid, f1 = tid + 256;
      xv0 = *(const float4*)(x + (row0 + (f0 >> 3)) * DIN + k0 + 32 + (f0 & 7) * 4);
      xv1 = *(const float4*)(x + (row0 + (f1 >> 3)) * DIN + k0 + 32 + (f1 & 7) * 4);
    }
    bf16x8 af[4], bfv[4];
#pragma unroll
    for (int mi = 0; mi < 4; ++mi)
      af[mi] = *(const bf16x8*)(As + (mi * 16 + l15) * 64 + q * 16);
#pragma unroll
    for (int ni = 0; ni < 4; ++ni)
      bfv[ni] = *(const bf16x8*)(Bs + (wc + ni * 16 + l15) * 64 + q * 16);
#pragma unroll
    for (int mi = 0; mi < 4; ++mi)
#pragma unroll
      for (int ni = 0; ni < 4; ++ni)
        acc[mi][ni] = __builtin_amdgcn_mfma_f32_16x16x32_bf16(
            af[mi], bfv[ni], acc[mi][ni], 0, 0, 0);
    __syncthreads();
  }

  // ============ phase 1.5: relu+bias -> xp [64][XPS] bf16 ============
  unsigned short* xp = (unsigned short*)smem;
#pragma unroll
  for (int ni = 0; ni < 4; ++ni) {
    const int col = wc + ni * 16 + l15;
    const float bb = bi[col];
#pragma unroll
    for (int mi = 0; mi < 4; ++mi)
#pragma unroll
      for (int reg = 0; reg < 4; ++reg) {
        const int row = mi * 16 + q * 4 + reg;
        xp[row * XPS + col] = f2bf(fmaxf(acc[ni < 2 ? mi : mi][ni][reg] + bb, 0.f));
      }
  }
  __syncthreads();

  // ============ phase 2: u = xp @ B (B frags from L2) ============
#pragma unroll
  for (int i = 0; i < 4; ++i)
#pragma unroll
    for (int j = 0; j < 4; ++j) acc[i][j] = f32x4{0.f, 0.f, 0.f, 0.f};
  for (int k0 = 0; k0 < PP; k0 += 32) {
    bf16x8 af[4], bfv[4];
#pragma unroll
    for (int mi = 0; mi < 4; ++mi)
      af[mi] = *(const bf16x8*)(xp + (mi * 16 + l15) * XPS + k0 + q * 8);
#pragma unroll
    for (int ni = 0; ni < 4; ++ni)
      bfv[ni] = *(const bf16x8*)(B_bT + (size_t)(wc + ni * 16 + l15) * PP + k0 + q * 8);
#pragma unroll
    for (int mi = 0; mi < 4; ++mi)
#pragma unroll
      for (int ni = 0; ni < 4; ++ni)
        acc[mi][ni] = __builtin_amdgcn_mfma_f32_16x16x32_bf16(
            af[mi], bfv[ni], acc[mi][ni], 0, 0, 0);
  }

  // ============ phase 3: register scan (zero-init local) ============
  // lane owns column col = wc+ni*16+l15, rows mi*16 + q*4 + reg
  float aC[4], Wz[4];
#pragma unroll
  for (int ni = 0; ni < 4; ++ni) aC[ni] = a[wc + ni * 16 + l15];
#pragma unroll
  for (int ni = 0; ni < 4; ++ni) {
    const float A = aC[ni];
    const float A2 = A * A, A4 = A2 * A2, A8 = A4 * A4, A16 = A8 * A8;
    const float A4q = ((q & 1) ? A4 : 1.f) * ((q & 2) ? A8 : 1.f);
    float W = 0.f;  // state entering current 16-row block (zero-init chain)
#pragma unroll
    for (int mi = 0; mi < 4; ++mi) {
      f32x4 v = acc[mi][ni];
      v.y = fmaf(A, v.x, v.y);
      v.z = fmaf(A, v.y, v.z);
      v.w = fmaf(A, v.z, v.w);
      const float E = v.w;
      const float E0 = __shfl(E, l15, 64);
      const float E1 = __shfl(E, l15 + 16, 64);
      const float E2 = __shfl(E, l15 + 32, 64);
      const float E3 = __shfl(E, l15 + 48, 64);
      const float s1 = E0, s2 = fmaf(A4, s1, E1), s3 = fmaf(A4, s2, E2);
      const float s4 = fmaf(A4, s3, E3);  // 16-row block total
      const float Sq = (q == 0) ? 0.f : (q == 1) ? s1 : (q == 2) ? s2 : s3;
      const float sin_ = fmaf(A4q, W, Sq);  // state entering lane's 4 rows
      v.x = fmaf(A, sin_, v.x);
      v.y = fmaf(A2, sin_, v.y);
      v.z = fmaf(A2 * A, sin_, v.z);
      v.w = fmaf(A4, sin_, v.w);
      acc[mi][ni] = v;
      W = fmaf(A16, W, s4);
    }
    Wz[ni] = W;  // full 64-row zero-init total == chunk carry
  }
  // publish carry, then flag
  if (q == 0) {
#pragma unroll
    for (int ni = 0; ni < 4; ++ni)
      __hip_atomic_store(&carry_g[(size_t)bc * HHH + wc + ni * 16 + l15],
                         Wz[ni], __ATOMIC_RELAXED, __HIP_MEMORY_SCOPE_AGENT);
  }
  __syncthreads();
  if (tid == 0) {
    __threadfence();
    __hip_atomic_store(&flag_g[bc], 1, __ATOMIC_RELEASE, __HIP_MEMORY_SCOPE_AGENT);
  }
  if (tid < c) {
    while (__hip_atomic_load(&flag_g[b * NCH + tid], __ATOMIC_ACQUIRE,
                             __HIP_MEMORY_SCOPE_AGENT) == 0)
      __builtin_amdgcn_s_sleep(8);
  }
  __syncthreads();
  // per-column incoming state P (thread t -> column t), Horner over carries
  {
    const int colp = tid;
    const float A = a[colp];
    float t1 = A;
#pragma unroll
    for (int j = 0; j < 6; ++j) t1 *= t1;  // A^64
    const float A64 = t1, A128 = A64 * A64, A256 = A128 * A128;
    const float* cg = carry_g + (size_t)b * NCH * HHH + colp;
    float P = 0.f;
    int j = 0;
    for (; j + 4 <= c; j += 4) {
      const float c0 = ld_carry(cg + (size_t)j * HHH);
      const float c1 = ld_carry(cg + (size_t)(j + 1) * HHH);
      const float c2 = ld_carry(cg + (size_t)(j + 2) * HHH);
      const float c3 = ld_carry(cg + (size_t)(j + 3) * HHH);
      P = fmaf(A256, P, fmaf(A64, fmaf(A64, fmaf(A64, c0, c1), c2), c3));
    }
    for (; j < c; ++j) P = fmaf(A64, P, ld_carry(cg + (size_t)j * HHH));
    PL[colp] = P;
  }
  __syncthreads();
  // fixup: h_row += A^(row+1) * P,  row = 16*mi + 4*q + reg
#pragma unroll
  for (int ni = 0; ni < 4; ++ni) {
    const float A = aC[ni];
    const float A2 = A * A, A4 = A2 * A2, A8 = A4 * A4, A16 = A8 * A8;
    const float A4q = ((q & 1) ? A4 : 1.f) * ((q & 2) ? A8 : 1.f);
    const float P = PL[wc + ni * 16 + l15];
    float fm = A4q * A * P;  // A^(4q+1) * P
#pragma unroll
    for (int mi = 0; mi < 4; ++mi) {
      f32x4 v = acc[mi][ni];
      v.x += fm;
      v.y = fmaf(A, fm, v.y);
      v.z = fmaf(A2, fm, v.z);
      v.w = fmaf(A2 * A, fm, v.w);
      acc[mi][ni] = v;
      fm *= A16;
    }
  }
  __syncthreads();  // PL consumed; xp region about to be overwritten

  // ============ phase 4: out = hs @ CWT^T + bo ============
  unsigned short* hsL = (unsigned short*)smem;  // [64][XPS] bf16
#pragma unroll
  for (int ni = 0; ni < 4; ++ni) {
    const int col = wc + ni * 16 + l15;
#pragma unroll
    for (int mi = 0; mi < 4; ++mi)
#pragma unroll
      for (int reg = 0; reg < 4; ++reg)
        hsL[(mi * 16 + q * 4 + reg) * XPS + col] = f2bf(acc[mi][ni][reg]);
  }
  __syncthreads();

#pragma unroll
  for (int g = 0; g < 2; ++g) {
    const int gc0 = wave * 128 + g * 64;
    f32x4 oacc[4][4];
#pragma unroll
    for (int i = 0; i < 4; ++i)
#pragma unroll
      for (int j = 0; j < 4; ++j) oacc[i][j] = f32x4{0.f, 0.f, 0.f, 0.f};
    for (int k0 = 0; k0 < HHH; k0 += 32) {
      bf16x8 af[4], bfv[4];
#pragma unroll
      for (int mi = 0; mi < 4; ++mi)
        af[mi] = *(const bf16x8*)(hsL + (mi * 16 + l15) * XPS + k0 + q * 8);
#pragma unroll
      for (int ni = 0; ni < 4; ++ni)
        bfv[ni] = *(const bf16x8*)(CWT_b + (size_t)(gc0 + ni * 16 + l15) * HHH + k0 + q * 8);
#pragma unroll
      for (int mi = 0; mi < 4; ++mi)
#pragma unroll
        for (int ni = 0; ni < 4; ++ni)
          oacc[mi][ni] = __builtin_amdgcn_mfma_f32_16x16x32_bf16(
              af[mi], bfv[ni], oacc[mi][ni], 0, 0, 0);
    }
#pragma unroll
    for (int ni = 0; ni < 4; ++ni) {
      const int ocol = gc0 + ni * 16 + l15;
      const float bb = bo[ocol];
#pragma unroll
      for (int mi = 0; mi < 4; ++mi)
#pragma unroll
        for (int reg = 0; reg < 4; ++reg) {
          const int row = mi * 16 + q * 4 + reg;
          out[(row0 + row) * DOUT + ocol] = oacc[mi][ni][reg] + bb;
        }
    }
  }
}

// ---------------------------------------------------------------------------
extern "C" void kernel_launch(void* const* d_in, const int* in_sizes, int n_in,
                              void* d_out, int out_size, void* d_ws,
                              size_t ws_size, hipStream_t stream) {
  const float* x  = (const float*)d_in[0];
  const float* a  = (const float*)d_in[1];
  const float* Bm = (const float*)d_in[2];
  const float* Cm = (const float*)d_in[3];
  const float* Wi = (const float*)d_in[4];
  const float* bi = (const float*)d_in[5];
  const float* Wo = (const float*)d_in[6];
  const float* bo = (const float*)d_in[7];
  float* out = (float*)d_out;

  char* ws = (char*)d_ws;
  unsigned short* Wi_b  = (unsigned short*)ws; ws += (size_t)PP * DIN * 2;
  unsigned short* B_bT  = (unsigned short*)ws; ws += (size_t)HHH * PP * 2;
  unsigned short* CWT_b = (unsigned short*)ws; ws += (size_t)DOUT * HHH * 2;
  float* carry_g = (float*)ws; ws += (size_t)NBLK * HHH * 4;
  int* flag_g = (int*)ws;

  prep_k<<<393, 256, 0, stream>>>(Wi, Wo, Cm, Bm, Wi_b, B_bT, CWT_b, flag_g);
  s4_mega<<<NBLK, 256, 0, stream>>>(x, a, Wi_b, bi, B_bT, CWT_b, bo, out,
                                    carry_g, flag_g);
}